// Round 1
// baseline (631.743 us; speedup 1.0000x reference)
//
#include <hip/hip_runtime.h>

// MoEAttentionBlock — fp32 baseline, structured for later MFMA upgrade.
// B=4 N=512 H=1024 NH=16 E=8 DH=64, T=2048 tokens.

constexpr int Bsz  = 4;
constexpr int Nseq = 512;
constexpr int Hdim = 1024;
constexpr int NHd  = 16;
constexpr int Ex   = 8;
constexpr int DHd  = 64;
constexpr int T    = Bsz * Nseq;   // 2048
constexpr int H3   = 3 * Hdim;     // 3072
constexpr int MAX_TILES = 96;      // sum ceil(c_e/32) <= 71

// ---------------- init: zero expert counts (ws is poisoned, not re-zeroed) ---------
__global__ void init_kernel(int* counts) {
  if (threadIdx.x < Ex) counts[threadIdx.x] = 0;
}

// ---------------- gating: logits -> softmax -> top-1 prob & expert ----------------
__global__ __launch_bounds__(64) void gate_kernel(
    const float* __restrict__ x, const float* __restrict__ wg,
    float* __restrict__ prob, int* __restrict__ expert, int* __restrict__ counts) {
  int t = blockIdx.x;
  int l = threadIdx.x;
  const float* xr = x + (size_t)t * Hdim;
  float acc[Ex] = {0, 0, 0, 0, 0, 0, 0, 0};
  for (int h = l; h < Hdim; h += 64) {
    float xv = xr[h];
    const float4* wr = (const float4*)(wg + (size_t)h * Ex);
    float4 w0 = wr[0], w1 = wr[1];
    acc[0] += xv * w0.x; acc[1] += xv * w0.y; acc[2] += xv * w0.z; acc[3] += xv * w0.w;
    acc[4] += xv * w1.x; acc[5] += xv * w1.y; acc[6] += xv * w1.z; acc[7] += xv * w1.w;
  }
#pragma unroll
  for (int e = 0; e < Ex; e++) {
#pragma unroll
    for (int off = 32; off > 0; off >>= 1) acc[e] += __shfl_down(acc[e], off);
  }
  if (l == 0) {
    float m = acc[0]; int mi = 0;
#pragma unroll
    for (int e = 1; e < Ex; e++) if (acc[e] > m) { m = acc[e]; mi = e; }  // first-max, matches jnp.argmax
    float s = 0.f;
#pragma unroll
    for (int e = 0; e < Ex; e++) s += expf(acc[e] - m);
    prob[t]   = 1.0f / s;    // softmax prob of the argmax expert
    expert[t] = mi;
    atomicAdd(&counts[mi], 1);
  }
}

// ---------------- offsets + tile map (single thread; 8 experts, <=71 tiles) -------
__global__ void offsets_kernel(const int* __restrict__ counts, int* offs, int* cursor,
                               int* meta, int* tile_e, int* tile_r) {
  int o = 0, nt = 0;
  for (int e = 0; e < Ex; e++) {
    offs[e] = o; cursor[e] = o;
    int c = counts[e];
    for (int r = 0; r < c; r += 32) { tile_e[nt] = e; tile_r[nt] = o + r; nt++; }
    o += c;
  }
  offs[Ex] = o;
  meta[0] = nt;
}

// ---------------- scatter tokens into expert-grouped order ------------------------
__global__ __launch_bounds__(256) void scatter_kernel(
    const int* __restrict__ expert, int* cursor, int* __restrict__ perm) {
  int t = blockIdx.x * 256 + threadIdx.x;
  if (t < T) {
    int slot = atomicAdd(&cursor[expert[t]], 1);
    perm[slot] = t;
  }
}

// ---------------- grouped GEMM: Y[tok] = prob[tok] * (X[tok] @ W[e] + b[e]) --------
// BM=32 tokens (gathered via perm), BN=128 cols, BK=32. 256 threads, 4x4 microtile.
__global__ __launch_bounds__(256) void moe_gemm_kernel(
    const float* __restrict__ X, const float* __restrict__ W,
    const float* __restrict__ bias, const float* __restrict__ prob,
    const int* __restrict__ perm, const int* __restrict__ offs,
    const int* __restrict__ meta, const int* __restrict__ tile_e,
    const int* __restrict__ tile_r,
    float* __restrict__ Y, int Ncols) {
  int tileIdx = blockIdx.y;
  if (tileIdx >= meta[0]) return;
  int e    = tile_e[tileIdx];
  int row0 = tile_r[tileIdx];
  int rows = offs[e + 1] - row0; if (rows > 32) rows = 32;
  int col0 = blockIdx.x * 128;

  __shared__ float Xs[32][40];    // stride 40 floats = 160B, 16B-aligned rows
  __shared__ float Ws[32][136];   // stride 136 floats = 544B, 16B-aligned rows

  int tid = threadIdx.x;
  int tx = tid & 31, ty = tid >> 5;

  int lr = tid >> 3;                 // 0..31 : X row this thread stages
  int lk = (tid & 7) * 4;            // 0..28 : k offset (float4)
  int lrow = row0 + (lr < rows ? lr : rows - 1);  // clamp: always valid data
  int ltok = perm[lrow];
  const float* xrow  = X + (size_t)ltok * Hdim;
  const float* wbase = W + ((size_t)e * Hdim) * Ncols + col0;

  float acc[4][4] = {};

  for (int k0 = 0; k0 < Hdim; k0 += 32) {
    *(float4*)&Xs[lr][lk] = *(const float4*)(xrow + k0 + lk);
#pragma unroll
    for (int i = 0; i < 4; i++) {
      int f = i * 256 + tid;
      int kr = f >> 5, c4 = (f & 31) * 4;
      *(float4*)&Ws[kr][c4] = *(const float4*)(wbase + (size_t)(k0 + kr) * Ncols + c4);
    }
    __syncthreads();
#pragma unroll
    for (int kk4 = 0; kk4 < 8; kk4++) {
      float a[4][4];
#pragma unroll
      for (int i = 0; i < 4; i++) {
        float4 t4 = *(const float4*)&Xs[ty * 4 + i][kk4 * 4];
        a[i][0] = t4.x; a[i][1] = t4.y; a[i][2] = t4.z; a[i][3] = t4.w;
      }
#pragma unroll
      for (int m = 0; m < 4; m++) {
        float4 bv = *(const float4*)&Ws[kk4 * 4 + m][tx * 4];
        acc[0][0] += a[0][m] * bv.x; acc[0][1] += a[0][m] * bv.y; acc[0][2] += a[0][m] * bv.z; acc[0][3] += a[0][m] * bv.w;
        acc[1][0] += a[1][m] * bv.x; acc[1][1] += a[1][m] * bv.y; acc[1][2] += a[1][m] * bv.z; acc[1][3] += a[1][m] * bv.w;
        acc[2][0] += a[2][m] * bv.x; acc[2][1] += a[2][m] * bv.y; acc[2][2] += a[2][m] * bv.z; acc[2][3] += a[2][m] * bv.w;
        acc[3][0] += a[3][m] * bv.x; acc[3][1] += a[3][m] * bv.y; acc[3][2] += a[3][m] * bv.z; acc[3][3] += a[3][m] * bv.w;
      }
    }
    __syncthreads();
  }

#pragma unroll
  for (int i = 0; i < 4; i++) {
    int r = ty * 4 + i;
    if (r < rows) {
      int tok = perm[row0 + r];
      float p = prob[tok];
      float4 bv = *(const float4*)(bias + (size_t)e * Ncols + col0 + tx * 4);
      float4 o;
      o.x = p * (acc[i][0] + bv.x);
      o.y = p * (acc[i][1] + bv.y);
      o.z = p * (acc[i][2] + bv.z);
      o.w = p * (acc[i][3] + bv.w);
      *(float4*)(Y + (size_t)tok * Ncols + col0 + tx * 4) = o;
    }
  }
}

// ---------------- attention: scores + mask + softmax + probs-out + PV -------------
// block = (qt 0..15, h 0..15, b 0..3), 256 threads, 32 q-rows per block.
__global__ __launch_bounds__(256) void attn_kernel(
    const float* __restrict__ qkv, const int* __restrict__ attn_mask,
    const int* __restrict__ kp_mask, float* __restrict__ probs_out,
    float* __restrict__ ctx) {
  int qt = blockIdx.x, h = blockIdx.y, b = blockIdx.z;
  int tid = threadIdx.x;

  __shared__ float Qs[32][68];   // 68 floats = 272B rows (16B aligned)
  __shared__ float Ks[64][68];   // reused for K then V tiles
  __shared__ float S[32][512];   // full score rows

  // load Q tile pre-scaled by 1/sqrt(DH)
  {
    int r = tid >> 3, c = (tid & 7) * 8;
    int t = b * Nseq + qt * 32 + r;
    const float* src = qkv + (size_t)t * H3 + h * DHd + c;
    float4 v0 = *(const float4*)(src);
    float4 v1 = *(const float4*)(src + 4);
    const float sc = 0.125f;
    float4 o0 = {v0.x * sc, v0.y * sc, v0.z * sc, v0.w * sc};
    float4 o1 = {v1.x * sc, v1.y * sc, v1.z * sc, v1.w * sc};
    *(float4*)&Qs[r][c]     = o0;
    *(float4*)&Qs[r][c + 4] = o1;
  }

  int q0  = (tid >> 4) * 2;   // 2 q-rows per thread
  int klo = tid & 15;         // keys klo + 16j (2-way LDS aliasing = free)

  for (int kt = 0; kt < 8; kt++) {
    __syncthreads();
#pragma unroll
    for (int i = 0; i < 4; i++) {
      int f = i * 256 + tid, kr = f >> 4, c = (f & 15) * 4;
      int tk = b * Nseq + kt * 64 + kr;
      *(float4*)&Ks[kr][c] = *(const float4*)(qkv + (size_t)tk * H3 + Hdim + h * DHd + c);
    }
    __syncthreads();
    float s0[4] = {0, 0, 0, 0}, s1[4] = {0, 0, 0, 0};
#pragma unroll
    for (int d4 = 0; d4 < 16; d4++) {
      float4 qa = *(const float4*)&Qs[q0][d4 * 4];
      float4 qb = *(const float4*)&Qs[q0 + 1][d4 * 4];
#pragma unroll
      for (int j = 0; j < 4; j++) {
        float4 kv = *(const float4*)&Ks[klo + 16 * j][d4 * 4];
        s0[j] += qa.x * kv.x + qa.y * kv.y + qa.z * kv.z + qa.w * kv.w;
        s1[j] += qb.x * kv.x + qb.y * kv.y + qb.z * kv.z + qb.w * kv.w;
      }
    }
#pragma unroll
    for (int j = 0; j < 4; j++) {
      int kcol = kt * 64 + klo + 16 * j;
      int kpm = kp_mask[b * Nseq + kcol];
#pragma unroll
      for (int i = 0; i < 2; i++) {
        int qrow = qt * 32 + q0 + i;
        int am = attn_mask[qrow * Nseq + kcol];
        float biasv = (am | kpm) ? -10000.0f : 0.0f;
        S[q0 + i][kcol] = (i == 0 ? s0[j] : s1[j]) + biasv;
      }
    }
  }
  __syncthreads();

  // softmax: 8 consecutive lanes per row
  {
    int r = tid >> 3, g = tid & 7;
    float m = -3.0e38f;
    for (int c = g; c < Nseq; c += 8) m = fmaxf(m, S[r][c]);
#pragma unroll
    for (int off = 1; off < 8; off <<= 1) m = fmaxf(m, __shfl_xor(m, off));
    float sum = 0.f;
    for (int c = g; c < Nseq; c += 8) {
      float p = expf(S[r][c] - m);
      S[r][c] = p;
      sum += p;
    }
#pragma unroll
    for (int off = 1; off < 8; off <<= 1) sum += __shfl_xor(sum, off);
    float inv = 1.0f / sum;
    for (int c = g; c < Nseq; c += 8) S[r][c] *= inv;
  }
  __syncthreads();

  // write attn_probs (coalesced; S layout == output row layout)
  {
    float* dst = probs_out + (((size_t)(b * NHd + h)) * Nseq + qt * 32) * Nseq;
    const float* src = &S[0][0];
#pragma unroll
    for (int i = 0; i < 16; i++) {
      int idx = (i * 256 + tid) * 4;
      *(float4*)(dst + idx) = *(const float4*)(src + idx);
    }
  }

  // PV: ctx[32][64] = P @ V ; thread owns 2 q-rows x 4 contiguous d
  float pacc[2][4] = {{0, 0, 0, 0}, {0, 0, 0, 0}};
  int dq = tid & 15;
  for (int kt = 0; kt < 8; kt++) {
    __syncthreads();
#pragma unroll
    for (int i = 0; i < 4; i++) {
      int f = i * 256 + tid, kr = f >> 4, c = (f & 15) * 4;
      int tk = b * Nseq + kt * 64 + kr;
      *(float4*)&Ks[kr][c] = *(const float4*)(qkv + (size_t)tk * H3 + 2 * Hdim + h * DHd + c);
    }
    __syncthreads();
#pragma unroll 4
    for (int k = 0; k < 64; k++) {
      float p0 = S[q0][kt * 64 + k], p1 = S[q0 + 1][kt * 64 + k];
      float4 vv = *(const float4*)&Ks[k][dq * 4];
      pacc[0][0] += p0 * vv.x; pacc[0][1] += p0 * vv.y; pacc[0][2] += p0 * vv.z; pacc[0][3] += p0 * vv.w;
      pacc[1][0] += p1 * vv.x; pacc[1][1] += p1 * vv.y; pacc[1][2] += p1 * vv.z; pacc[1][3] += p1 * vv.w;
    }
  }
#pragma unroll
  for (int i = 0; i < 2; i++) {
    int tq = b * Nseq + qt * 32 + q0 + i;
    float4 o = {pacc[i][0], pacc[i][1], pacc[i][2], pacc[i][3]};
    *(float4*)(ctx + (size_t)tq * Hdim + h * DHd + dq * 4) = o;
  }
}

// ---------------- host ------------------------------------------------------------
extern "C" void kernel_launch(void* const* d_in, const int* in_sizes, int n_in,
                              void* d_out, int out_size, void* d_ws, size_t ws_size,
                              hipStream_t stream) {
  const float* hidden   = (const float*)d_in[0];
  const int*   attn_m   = (const int*)d_in[1];
  const int*   kp_m     = (const int*)d_in[2];
  const float* w_gate   = (const float*)d_in[3];
  const float* w_qkv    = (const float*)d_in[4];
  const float* b_qkv    = (const float*)d_in[5];
  const float* w_dense  = (const float*)d_in[6];
  const float* b_dense  = (const float*)d_in[7];

  float* out       = (float*)d_out;                       // [T, H]
  float* probs_out = out + (size_t)T * Hdim;              // [B, NH, N, N]

  // workspace layout (floats): prob[0..2047], pad, qkv[T*3H], ctx[T*H], then ints
  float* wsf  = (float*)d_ws;
  float* prob = wsf;
  float* qkv  = wsf + 4096;
  float* ctx  = qkv + (size_t)T * H3;
  int*   ip     = (int*)(ctx + (size_t)T * Hdim);
  int*   expert = ip;
  int*   perm   = ip + T;
  int*   counts = ip + 2 * T;
  int*   offs   = counts + 8;
  int*   cursor = offs + 12;
  int*   meta   = cursor + 8;
  int*   tile_e = meta + 4;
  int*   tile_r = tile_e + MAX_TILES;

  init_kernel<<<1, 64, 0, stream>>>(counts);
  gate_kernel<<<T, 64, 0, stream>>>(hidden, w_gate, prob, expert, counts);
  offsets_kernel<<<1, 1, 0, stream>>>(counts, offs, cursor, meta, tile_e, tile_r);
  scatter_kernel<<<T / 256, 256, 0, stream>>>(expert, cursor, perm);
  moe_gemm_kernel<<<dim3(H3 / 128, 72), 256, 0, stream>>>(
      hidden, w_qkv, b_qkv, prob, perm, offs, meta, tile_e, tile_r, qkv, H3);
  attn_kernel<<<dim3(16, NHd, Bsz), 256, 0, stream>>>(qkv, attn_m, kp_m, probs_out, ctx);
  moe_gemm_kernel<<<dim3(Hdim / 128, 72), 256, 0, stream>>>(
      ctx, w_dense, b_dense, prob, perm, offs, meta, tile_e, tile_r, out, Hdim);
}

// Round 2
// 359.665 us; speedup vs baseline: 1.7565x; 1.7565x over previous
//
#include <hip/hip_runtime.h>

// MoEAttentionBlock r2: bf16-MFMA grouped MoE GEMMs + bf16-S attention.
// B=4 N=512 H=1024 NH=16 E=8 DH=64, T=2048 tokens.

typedef short short8 __attribute__((ext_vector_type(8)));
typedef float f32x4 __attribute__((ext_vector_type(4)));

constexpr int Bsz  = 4;
constexpr int Nseq = 512;
constexpr int Hdim = 1024;
constexpr int NHd  = 16;
constexpr int Ex   = 8;
constexpr int DHd  = 64;
constexpr int T    = Bsz * Nseq;   // 2048
constexpr int H3   = 3 * Hdim;     // 3072
constexpr int BM   = 128;          // GEMM row-tile (tokens)
constexpr int MAX_T = 24;          // max row tiles: <= 16+7

__device__ inline unsigned short f2bf(float f) {
  union { float f; unsigned u; } v{f};
  unsigned r = v.u + 0x7fffu + ((v.u >> 16) & 1u);   // RNE
  return (unsigned short)(r >> 16);
}
__device__ inline float bf2f(unsigned short s) {
  union { unsigned u; float f; } v{(unsigned)s << 16};
  return v.f;
}

// ---------------- init: zero expert counts (ws poisoned once, never re-zeroed) ----
__global__ void init_kernel(int* counts) {
  if (threadIdx.x < Ex) counts[threadIdx.x] = 0;
}

// ---------------- gating: logits -> softmax -> top-1 prob & expert ----------------
__global__ __launch_bounds__(64) void gate_kernel(
    const float* __restrict__ x, const float* __restrict__ wg,
    float* __restrict__ prob, int* __restrict__ expert, int* __restrict__ counts) {
  int t = blockIdx.x;
  int l = threadIdx.x;
  const float* xr = x + (size_t)t * Hdim;
  float acc[Ex] = {0, 0, 0, 0, 0, 0, 0, 0};
  for (int h = l; h < Hdim; h += 64) {
    float xv = xr[h];
    const float4* wr = (const float4*)(wg + (size_t)h * Ex);
    float4 w0 = wr[0], w1 = wr[1];
    acc[0] += xv * w0.x; acc[1] += xv * w0.y; acc[2] += xv * w0.z; acc[3] += xv * w0.w;
    acc[4] += xv * w1.x; acc[5] += xv * w1.y; acc[6] += xv * w1.z; acc[7] += xv * w1.w;
  }
#pragma unroll
  for (int e = 0; e < Ex; e++) {
#pragma unroll
    for (int off = 32; off > 0; off >>= 1) acc[e] += __shfl_down(acc[e], off);
  }
  if (l == 0) {
    float m = acc[0]; int mi = 0;
#pragma unroll
    for (int e = 1; e < Ex; e++) if (acc[e] > m) { m = acc[e]; mi = e; }  // first-max == jnp.argmax
    float s = 0.f;
#pragma unroll
    for (int e = 0; e < Ex; e++) s += expf(acc[e] - m);
    prob[t]   = 1.0f / s;
    expert[t] = mi;
    atomicAdd(&counts[mi], 1);
  }
}

// ---------------- offsets + BM=128 tile map ---------------------------------------
__global__ void offsets_kernel(const int* __restrict__ counts, int* offs, int* cursor,
                               int* meta, int* tile_e, int* tile_r) {
  int o = 0, nt = 0;
  for (int e = 0; e < Ex; e++) {
    offs[e] = o; cursor[e] = o;
    int c = counts[e];
    for (int r = 0; r < c; r += BM) { tile_e[nt] = e; tile_r[nt] = o + r; nt++; }
    o += c;
  }
  offs[Ex] = o;
  meta[0] = nt;
}

// ---------------- scatter tokens into expert-grouped order ------------------------
__global__ __launch_bounds__(256) void scatter_kernel(
    const int* __restrict__ expert, int* cursor, int* __restrict__ perm) {
  int t = blockIdx.x * 256 + threadIdx.x;
  if (t < T) {
    int slot = atomicAdd(&cursor[expert[t]], 1);
    perm[slot] = t;
  }
}

// ---------------- fp32 -> bf16 bulk convert ---------------------------------------
__global__ __launch_bounds__(256) void cvt_kernel(const float* __restrict__ x,
                                                  unsigned short* __restrict__ y, int n8) {
  int i = blockIdx.x * 256 + threadIdx.x;
  if (i < n8) {
    const float4* s = (const float4*)(x + (size_t)i * 8);
    float4 a = s[0], b = s[1];
    ushort4 lo = {f2bf(a.x), f2bf(a.y), f2bf(a.z), f2bf(a.w)};
    ushort4 hi = {f2bf(b.x), f2bf(b.y), f2bf(b.z), f2bf(b.w)};
    ushort4* d = (ushort4*)(y + (size_t)i * 8);
    d[0] = lo; d[1] = hi;
  }
}

// ---------------- grouped GEMM via MFMA: Y[tok] = p * (Xb[tok] @ W[e] + b[e]) -----
// BM=128 BN=128 BK=32, 256 thr = 4 waves (2x2), each wave 64x64 via 4x4 16x16 frags.
// A: bf16 [128][40] LDS (80B rows, 2-way free). B: W fp32 transposed-in-flight to
// bf16 [32][138] LDS (276B rows); frag reads 8x ds_read_u16 (69-dword stride, 2-way free).
__global__ __launch_bounds__(256) void moe_gemm_mfma(
    const unsigned short* __restrict__ Xb, const float* __restrict__ W,
    const float* __restrict__ bias, const float* __restrict__ prob,
    const int* __restrict__ perm, const int* __restrict__ offs,
    const int* __restrict__ meta, const int* __restrict__ tile_e,
    const int* __restrict__ tile_r,
    unsigned short* __restrict__ Ybf, float* __restrict__ Yf, int Ncols) {
  int tIdx = blockIdx.y;
  if (tIdx >= meta[0]) return;
  int e = tile_e[tIdx], row0 = tile_r[tIdx];
  int rows = offs[e + 1] - row0; if (rows > BM) rows = BM;
  int col0 = blockIdx.x * 128;

  __shared__ unsigned short As[128 * 40];
  __shared__ unsigned short Bs[32 * 138];
  __shared__ int   tok_s[128];
  __shared__ float p_s[128];

  int tid = threadIdx.x;
  if (tid < 128) {
    int rr = tid < rows ? tid : rows - 1;   // clamp: rows >= 1 always
    int tok = perm[row0 + rr];
    tok_s[tid] = tok; p_s[tid] = prob[tok];
  }
  __syncthreads();

  // A staging: 512 16B-chunks; thread handles chunks tid and tid+256.
  int ar0 = tid >> 2,        aq = tid & 3;
  int ar1 = (tid >> 2) + 64;
  const unsigned short* asrc0 = Xb + (size_t)tok_s[ar0] * Hdim + aq * 8;
  const unsigned short* asrc1 = Xb + (size_t)tok_s[ar1] * Hdim + aq * 8;
  // B staging: thread owns W row k=tid>>3, 16 cols at (tid&7)*16.
  int bkr = tid >> 3, bn16 = (tid & 7) * 16;
  const float* bsrc = W + ((size_t)e * Hdim + bkr) * Ncols + col0 + bn16;

  int lane = tid & 63, wave = tid >> 6;
  int wr = wave >> 1, wc = wave & 1;
  int l15 = lane & 15, l4 = lane >> 4;

  f32x4 acc[4][4] = {};

  for (int k0 = 0; k0 < Hdim; k0 += 32) {
    uint4 av0 = *(const uint4*)(asrc0 + k0);
    uint4 av1 = *(const uint4*)(asrc1 + k0);
    float4 w0 = *(const float4*)(bsrc + (size_t)k0 * Ncols + 0);
    float4 w1 = *(const float4*)(bsrc + (size_t)k0 * Ncols + 4);
    float4 w2 = *(const float4*)(bsrc + (size_t)k0 * Ncols + 8);
    float4 w3 = *(const float4*)(bsrc + (size_t)k0 * Ncols + 12);
    __syncthreads();   // previous tile's reads complete
    *(uint4*)&As[ar0 * 40 + aq * 8] = av0;
    *(uint4*)&As[ar1 * 40 + aq * 8] = av1;
    unsigned* brow = (unsigned*)&Bs[bkr * 138] + (bn16 >> 1);
    brow[0] = (unsigned)f2bf(w0.x) | ((unsigned)f2bf(w0.y) << 16);
    brow[1] = (unsigned)f2bf(w0.z) | ((unsigned)f2bf(w0.w) << 16);
    brow[2] = (unsigned)f2bf(w1.x) | ((unsigned)f2bf(w1.y) << 16);
    brow[3] = (unsigned)f2bf(w1.z) | ((unsigned)f2bf(w1.w) << 16);
    brow[4] = (unsigned)f2bf(w2.x) | ((unsigned)f2bf(w2.y) << 16);
    brow[5] = (unsigned)f2bf(w2.z) | ((unsigned)f2bf(w2.w) << 16);
    brow[6] = (unsigned)f2bf(w3.x) | ((unsigned)f2bf(w3.y) << 16);
    brow[7] = (unsigned)f2bf(w3.z) | ((unsigned)f2bf(w3.w) << 16);
    __syncthreads();

    short8 a[4];
#pragma unroll
    for (int m = 0; m < 4; m++)
      a[m] = *(const short8*)&As[(wr * 64 + m * 16 + l15) * 40 + l4 * 8];
#pragma unroll
    for (int n = 0; n < 4; n++) {
      const unsigned short* bp = &Bs[(l4 * 8) * 138 + wc * 64 + n * 16 + l15];
      short8 bfr;
      bfr[0] = bp[0];   bfr[1] = bp[138]; bfr[2] = bp[276]; bfr[3] = bp[414];
      bfr[4] = bp[552]; bfr[5] = bp[690]; bfr[6] = bp[828]; bfr[7] = bp[966];
#pragma unroll
      for (int m = 0; m < 4; m++)
        acc[m][n] = __builtin_amdgcn_mfma_f32_16x16x32_bf16(a[m], bfr, acc[m][n], 0, 0, 0);
    }
  }

  // epilogue: C/D layout col=lane&15, row=(lane>>4)*4+reg  [m89]
#pragma unroll
  for (int n = 0; n < 4; n++) {
    int colg = col0 + wc * 64 + n * 16 + l15;
    float bv = bias[(size_t)e * Ncols + colg];
#pragma unroll
    for (int m = 0; m < 4; m++) {
#pragma unroll
      for (int r = 0; r < 4; r++) {
        int row = wr * 64 + m * 16 + l4 * 4 + r;
        if (row < rows) {
          int tok = tok_s[row];
          float o = (acc[m][n][r] + bv) * p_s[row];
          if (Ybf) Ybf[(size_t)tok * Ncols + colg] = f2bf(o);
          else     Yf [(size_t)tok * Ncols + colg] = o;
        }
      }
    }
  }
}

// ---------------- attention: scores + mask + softmax + probs-out + PV -------------
// Same proven structure as r1; S now bf16 (LDS 89.5->57.5 KiB -> 2 blocks/CU),
// qkv in bf16, ctx out bf16.
__global__ __launch_bounds__(256) void attn_kernel(
    const unsigned short* __restrict__ qkvb, const int* __restrict__ attn_mask,
    const int* __restrict__ kp_mask, float* __restrict__ probs_out,
    unsigned short* __restrict__ ctxb) {
  int qt = blockIdx.x, h = blockIdx.y, b = blockIdx.z;
  int tid = threadIdx.x;

  __shared__ float Qs[32][68];
  __shared__ float Ks[64][68];            // K tile, then V tile
  __shared__ unsigned short S[32][512];   // scores/probs, bf16

  {
    int r = tid >> 3, c = (tid & 7) * 8;
    int t = b * Nseq + qt * 32 + r;
    uint4 v = *(const uint4*)(qkvb + (size_t)t * H3 + h * DHd + c);
    const unsigned short* u = (const unsigned short*)&v;
    const float sc = 0.125f;   // 1/sqrt(64)
    *(float4*)&Qs[r][c]     = {bf2f(u[0]) * sc, bf2f(u[1]) * sc, bf2f(u[2]) * sc, bf2f(u[3]) * sc};
    *(float4*)&Qs[r][c + 4] = {bf2f(u[4]) * sc, bf2f(u[5]) * sc, bf2f(u[6]) * sc, bf2f(u[7]) * sc};
  }

  int q0  = (tid >> 4) * 2;
  int klo = tid & 15;

  for (int kt = 0; kt < 8; kt++) {
    __syncthreads();
#pragma unroll
    for (int i = 0; i < 2; i++) {
      int f = i * 256 + tid;
      int kr = f >> 3, c = (f & 7) * 8;
      int tk = b * Nseq + kt * 64 + kr;
      uint4 v = *(const uint4*)(qkvb + (size_t)tk * H3 + Hdim + h * DHd + c);
      const unsigned short* u = (const unsigned short*)&v;
      *(float4*)&Ks[kr][c]     = {bf2f(u[0]), bf2f(u[1]), bf2f(u[2]), bf2f(u[3])};
      *(float4*)&Ks[kr][c + 4] = {bf2f(u[4]), bf2f(u[5]), bf2f(u[6]), bf2f(u[7])};
    }
    __syncthreads();
    float s0[4] = {0, 0, 0, 0}, s1[4] = {0, 0, 0, 0};
#pragma unroll
    for (int d4 = 0; d4 < 16; d4++) {
      float4 qa = *(const float4*)&Qs[q0][d4 * 4];
      float4 qb = *(const float4*)&Qs[q0 + 1][d4 * 4];
#pragma unroll
      for (int j = 0; j < 4; j++) {
        float4 kv = *(const float4*)&Ks[klo + 16 * j][d4 * 4];
        s0[j] += qa.x * kv.x + qa.y * kv.y + qa.z * kv.z + qa.w * kv.w;
        s1[j] += qb.x * kv.x + qb.y * kv.y + qb.z * kv.z + qb.w * kv.w;
      }
    }
#pragma unroll
    for (int j = 0; j < 4; j++) {
      int kcol = kt * 64 + klo + 16 * j;
      int kpm = kp_mask[b * Nseq + kcol];
      int am0 = attn_mask[(qt * 32 + q0) * Nseq + kcol];
      int am1 = attn_mask[(qt * 32 + q0 + 1) * Nseq + kcol];
      S[q0][kcol]     = f2bf(s0[j] + ((am0 | kpm) ? -10000.0f : 0.0f));
      S[q0 + 1][kcol] = f2bf(s1[j] + ((am1 | kpm) ? -10000.0f : 0.0f));
    }
  }
  __syncthreads();

  // softmax: 8 lanes per row
  {
    int r = tid >> 3, g = tid & 7;
    float m = -3.0e38f;
    for (int c = g; c < Nseq; c += 8) m = fmaxf(m, bf2f(S[r][c]));
#pragma unroll
    for (int off = 1; off < 8; off <<= 1) m = fmaxf(m, __shfl_xor(m, off));
    float sum = 0.f;
    for (int c = g; c < Nseq; c += 8) {
      float p = expf(bf2f(S[r][c]) - m);
      S[r][c] = f2bf(p);
      sum += p;
    }
#pragma unroll
    for (int off = 1; off < 8; off <<= 1) sum += __shfl_xor(sum, off);
    float inv = 1.0f / sum;
    for (int c = g; c < Nseq; c += 8) S[r][c] = f2bf(bf2f(S[r][c]) * inv);
  }
  __syncthreads();

  // attn_probs out (fp32), coalesced
  {
    float* dst = probs_out + (((size_t)(b * NHd + h)) * Nseq + qt * 32) * Nseq;
    const unsigned short* src = &S[0][0];
#pragma unroll
    for (int i = 0; i < 8; i++) {
      int off = (i * 256 + tid) * 8;
      uint4 v = *(const uint4*)(src + off);
      const unsigned short* u = (const unsigned short*)&v;
      *(float4*)(dst + off)     = {bf2f(u[0]), bf2f(u[1]), bf2f(u[2]), bf2f(u[3])};
      *(float4*)(dst + off + 4) = {bf2f(u[4]), bf2f(u[5]), bf2f(u[6]), bf2f(u[7])};
    }
  }

  // PV
  float pacc[2][4] = {{0, 0, 0, 0}, {0, 0, 0, 0}};
  int dq = tid & 15;
  for (int kt = 0; kt < 8; kt++) {
    __syncthreads();
#pragma unroll
    for (int i = 0; i < 2; i++) {
      int f = i * 256 + tid;
      int kr = f >> 3, c = (f & 7) * 8;
      int tk = b * Nseq + kt * 64 + kr;
      uint4 v = *(const uint4*)(qkvb + (size_t)tk * H3 + 2 * Hdim + h * DHd + c);
      const unsigned short* u = (const unsigned short*)&v;
      *(float4*)&Ks[kr][c]     = {bf2f(u[0]), bf2f(u[1]), bf2f(u[2]), bf2f(u[3])};
      *(float4*)&Ks[kr][c + 4] = {bf2f(u[4]), bf2f(u[5]), bf2f(u[6]), bf2f(u[7])};
    }
    __syncthreads();
#pragma unroll 4
    for (int k = 0; k < 64; k++) {
      float p0 = bf2f(S[q0][kt * 64 + k]), p1 = bf2f(S[q0 + 1][kt * 64 + k]);
      float4 vv = *(const float4*)&Ks[k][dq * 4];
      pacc[0][0] += p0 * vv.x; pacc[0][1] += p0 * vv.y; pacc[0][2] += p0 * vv.z; pacc[0][3] += p0 * vv.w;
      pacc[1][0] += p1 * vv.x; pacc[1][1] += p1 * vv.y; pacc[1][2] += p1 * vv.z; pacc[1][3] += p1 * vv.w;
    }
  }
#pragma unroll
  for (int i = 0; i < 2; i++) {
    int tq = b * Nseq + qt * 32 + q0 + i;
    ushort4 o = {f2bf(pacc[i][0]), f2bf(pacc[i][1]), f2bf(pacc[i][2]), f2bf(pacc[i][3])};
    *(ushort4*)(ctxb + (size_t)tq * Hdim + h * DHd + dq * 4) = o;
  }
}

// ---------------- host ------------------------------------------------------------
extern "C" void kernel_launch(void* const* d_in, const int* in_sizes, int n_in,
                              void* d_out, int out_size, void* d_ws, size_t ws_size,
                              hipStream_t stream) {
  const float* hidden   = (const float*)d_in[0];
  const int*   attn_m   = (const int*)d_in[1];
  const int*   kp_m     = (const int*)d_in[2];
  const float* w_gate   = (const float*)d_in[3];
  const float* w_qkv    = (const float*)d_in[4];
  const float* b_qkv    = (const float*)d_in[5];
  const float* w_dense  = (const float*)d_in[6];
  const float* b_dense  = (const float*)d_in[7];

  float* out       = (float*)d_out;                 // [T,H] fp32
  float* probs_out = out + (size_t)T * Hdim;        // [B,NH,N,N] fp32

  // ws: prob f32[2048] | Xb bf16[T*H] | qkvb bf16[T*3H] | ctxb bf16[T*H] | ints (~21 MB)
  float*          prob = (float*)d_ws;
  unsigned short* Xb   = (unsigned short*)(prob + 2048);
  unsigned short* qkvb = Xb + (size_t)T * Hdim;
  unsigned short* ctxb = qkvb + (size_t)T * H3;
  int*   ip     = (int*)(ctxb + (size_t)T * Hdim);
  int*   expert = ip;
  int*   perm   = ip + T;
  int*   counts = ip + 2 * T;
  int*   offs   = counts + 8;
  int*   cursor = offs + 12;
  int*   meta   = cursor + 8;
  int*   tile_e = meta + 4;
  int*   tile_r = tile_e + MAX_T;

  init_kernel<<<1, 64, 0, stream>>>(counts);
  gate_kernel<<<T, 64, 0, stream>>>(hidden, w_gate, prob, expert, counts);
  offsets_kernel<<<1, 1, 0, stream>>>(counts, offs, cursor, meta, tile_e, tile_r);
  scatter_kernel<<<T / 256, 256, 0, stream>>>(expert, cursor, perm);
  cvt_kernel<<<(T * Hdim / 8) / 256, 256, 0, stream>>>(hidden, Xb, T * Hdim / 8);
  moe_gemm_mfma<<<dim3(H3 / 128, MAX_T), 256, 0, stream>>>(
      Xb, w_qkv, b_qkv, prob, perm, offs, meta, tile_e, tile_r, qkvb, nullptr, H3);
  attn_kernel<<<dim3(16, NHd, Bsz), 256, 0, stream>>>(qkvb, attn_m, kp_m, probs_out, ctxb);
  moe_gemm_mfma<<<dim3(Hdim / 128, MAX_T), 256, 0, stream>>>(
      ctxb, w_dense, b_dense, prob, perm, offs, meta, tile_e, tile_r, nullptr, out, Hdim);
}

// Round 3
// 208.252 us; speedup vs baseline: 3.0335x; 1.7271x over previous
//
#include <hip/hip_runtime.h>

// MoEAttentionBlock r3: MFMA attention (QK^T + PV) + b128 B-frag GEMM.
// B=4 N=512 H=1024 NH=16 E=8 DH=64, T=2048 tokens.

typedef short short8 __attribute__((ext_vector_type(8)));
typedef float f32x4 __attribute__((ext_vector_type(4)));

constexpr int Bsz  = 4;
constexpr int Nseq = 512;
constexpr int Hdim = 1024;
constexpr int NHd  = 16;
constexpr int Ex   = 8;
constexpr int DHd  = 64;
constexpr int T    = Bsz * Nseq;   // 2048
constexpr int H3   = 3 * Hdim;     // 3072
constexpr int BM   = 128;          // GEMM row-tile (tokens)
constexpr int MAX_T = 24;          // sum ceil(c_e/128) <= 16+8

__device__ inline unsigned short f2bf(float f) {
  union { float f; unsigned u; } v{f};
  unsigned r = v.u + 0x7fffu + ((v.u >> 16) & 1u);   // RNE
  return (unsigned short)(r >> 16);
}
__device__ inline float bf2f(unsigned short s) {
  union { unsigned u; float f; } v{(unsigned)s << 16};
  return v.f;
}
__device__ inline unsigned packbf(float lo, float hi) {
  return (unsigned)f2bf(lo) | ((unsigned)f2bf(hi) << 16);
}

// ---------------- init ------------------------------------------------------------
__global__ void init_kernel(int* counts) {
  if (threadIdx.x < Ex) counts[threadIdx.x] = 0;
}

// ---------------- gating ----------------------------------------------------------
__global__ __launch_bounds__(64) void gate_kernel(
    const float* __restrict__ x, const float* __restrict__ wg,
    float* __restrict__ prob, int* __restrict__ expert, int* __restrict__ counts) {
  int t = blockIdx.x;
  int l = threadIdx.x;
  const float* xr = x + (size_t)t * Hdim;
  float acc[Ex] = {0, 0, 0, 0, 0, 0, 0, 0};
  for (int h = l; h < Hdim; h += 64) {
    float xv = xr[h];
    const float4* wr = (const float4*)(wg + (size_t)h * Ex);
    float4 w0 = wr[0], w1 = wr[1];
    acc[0] += xv * w0.x; acc[1] += xv * w0.y; acc[2] += xv * w0.z; acc[3] += xv * w0.w;
    acc[4] += xv * w1.x; acc[5] += xv * w1.y; acc[6] += xv * w1.z; acc[7] += xv * w1.w;
  }
#pragma unroll
  for (int e = 0; e < Ex; e++) {
#pragma unroll
    for (int off = 32; off > 0; off >>= 1) acc[e] += __shfl_down(acc[e], off);
  }
  if (l == 0) {
    float m = acc[0]; int mi = 0;
#pragma unroll
    for (int e = 1; e < Ex; e++) if (acc[e] > m) { m = acc[e]; mi = e; }  // first-max == jnp.argmax
    float s = 0.f;
#pragma unroll
    for (int e = 0; e < Ex; e++) s += expf(acc[e] - m);
    prob[t]   = 1.0f / s;
    expert[t] = mi;
    atomicAdd(&counts[mi], 1);
  }
}

// ---------------- offsets + BM=128 tile map ---------------------------------------
__global__ void offsets_kernel(const int* __restrict__ counts, int* offs, int* cursor,
                               int* meta, int* tile_e, int* tile_r) {
  int o = 0, nt = 0;
  for (int e = 0; e < Ex; e++) {
    offs[e] = o; cursor[e] = o;
    int c = counts[e];
    for (int r = 0; r < c; r += BM) { tile_e[nt] = e; tile_r[nt] = o + r; nt++; }
    o += c;
  }
  offs[Ex] = o;
  meta[0] = nt;
}

// ---------------- scatter ---------------------------------------------------------
__global__ __launch_bounds__(256) void scatter_kernel(
    const int* __restrict__ expert, int* cursor, int* __restrict__ perm) {
  int t = blockIdx.x * 256 + threadIdx.x;
  if (t < T) {
    int slot = atomicAdd(&cursor[expert[t]], 1);
    perm[slot] = t;
  }
}

// ---------------- fp32 -> bf16 bulk convert ---------------------------------------
__global__ __launch_bounds__(256) void cvt_kernel(const float* __restrict__ x,
                                                  unsigned short* __restrict__ y, int n8) {
  int i = blockIdx.x * 256 + threadIdx.x;
  if (i < n8) {
    const float4* s = (const float4*)(x + (size_t)i * 8);
    float4 a = s[0], b = s[1];
    ushort4 lo = {f2bf(a.x), f2bf(a.y), f2bf(a.z), f2bf(a.w)};
    ushort4 hi = {f2bf(b.x), f2bf(b.y), f2bf(b.z), f2bf(b.w)};
    ushort4* d = (ushort4*)(y + (size_t)i * 8);
    d[0] = lo; d[1] = hi;
  }
}

// ---------------- grouped GEMM via MFMA -------------------------------------------
// BM=128 BN=128 BK=32, 4 waves (2x2), each wave 64x64 via 4x4 16x16x32 frags.
// A: bf16 [128][40]. B: W fp32 transposed-in-flight to Bt[col][40] (k-pair packed
// dword writes, conflict-free); B-frag = single ds_read_b128.
__global__ __launch_bounds__(256) void moe_gemm_mfma(
    const unsigned short* __restrict__ Xb, const float* __restrict__ W,
    const float* __restrict__ bias, const float* __restrict__ prob,
    const int* __restrict__ perm, const int* __restrict__ offs,
    const int* __restrict__ meta, const int* __restrict__ tile_e,
    const int* __restrict__ tile_r,
    unsigned short* __restrict__ Ybf, float* __restrict__ Yf, int Ncols) {
  int tIdx = blockIdx.y;
  if (tIdx >= meta[0]) return;
  int e = tile_e[tIdx], row0 = tile_r[tIdx];
  int rows = offs[e + 1] - row0; if (rows > BM) rows = BM;
  int col0 = blockIdx.x * 128;

  __shared__ unsigned short As[128 * 40];
  __shared__ unsigned short Bt[128 * 40];
  __shared__ int   tok_s[128];
  __shared__ float p_s[128];

  int tid = threadIdx.x;
  if (tid < 128) {
    int rr = tid < rows ? tid : rows - 1;
    int tok = perm[row0 + rr];
    tok_s[tid] = tok; p_s[tid] = prob[tok];
  }
  __syncthreads();

  // A staging: thread handles rows tid>>2 and +64, 8 bf16 at (tid&3)*8.
  int ar0 = tid >> 2, aq = tid & 3;
  int ar1 = ar0 + 64;
  const unsigned short* asrc0 = Xb + (size_t)tok_s[ar0] * Hdim + aq * 8;
  const unsigned short* asrc1 = Xb + (size_t)tok_s[ar1] * Hdim + aq * 8;
  // B staging: thread owns k-pair kp (rows k0+2kp, k0+2kp+1), 8 cols at bc8.
  int kp = tid & 15, bc8 = (tid >> 4) * 8;
  const float* wb = W + (size_t)e * Hdim * Ncols + col0 + bc8;

  int lane = tid & 63, wave = tid >> 6;
  int wr = wave >> 1, wc = wave & 1;
  int l15 = lane & 15, l4 = lane >> 4;

  f32x4 acc[4][4] = {};

  for (int k0 = 0; k0 < Hdim; k0 += 32) {
    uint4 av0 = *(const uint4*)(asrc0 + k0);
    uint4 av1 = *(const uint4*)(asrc1 + k0);
    const float* r0 = wb + (size_t)(k0 + 2 * kp) * Ncols;
    float4 wa0 = *(const float4*)(r0);
    float4 wa1 = *(const float4*)(r0 + 4);
    float4 wb0 = *(const float4*)(r0 + Ncols);
    float4 wb1 = *(const float4*)(r0 + Ncols + 4);
    __syncthreads();   // previous tile's frag reads complete
    *(uint4*)&As[ar0 * 40 + aq * 8] = av0;
    *(uint4*)&As[ar1 * 40 + aq * 8] = av1;
    *(unsigned*)&Bt[(bc8 + 0) * 40 + 2 * kp] = packbf(wa0.x, wb0.x);
    *(unsigned*)&Bt[(bc8 + 1) * 40 + 2 * kp] = packbf(wa0.y, wb0.y);
    *(unsigned*)&Bt[(bc8 + 2) * 40 + 2 * kp] = packbf(wa0.z, wb0.z);
    *(unsigned*)&Bt[(bc8 + 3) * 40 + 2 * kp] = packbf(wa0.w, wb0.w);
    *(unsigned*)&Bt[(bc8 + 4) * 40 + 2 * kp] = packbf(wa1.x, wb1.x);
    *(unsigned*)&Bt[(bc8 + 5) * 40 + 2 * kp] = packbf(wa1.y, wb1.y);
    *(unsigned*)&Bt[(bc8 + 6) * 40 + 2 * kp] = packbf(wa1.z, wb1.z);
    *(unsigned*)&Bt[(bc8 + 7) * 40 + 2 * kp] = packbf(wa1.w, wb1.w);
    __syncthreads();

    short8 a[4];
#pragma unroll
    for (int m = 0; m < 4; m++)
      a[m] = *(const short8*)&As[(wr * 64 + m * 16 + l15) * 40 + l4 * 8];
#pragma unroll
    for (int n = 0; n < 4; n++) {
      short8 bfr = *(const short8*)&Bt[(wc * 64 + n * 16 + l15) * 40 + l4 * 8];
#pragma unroll
      for (int m = 0; m < 4; m++)
        acc[m][n] = __builtin_amdgcn_mfma_f32_16x16x32_bf16(a[m], bfr, acc[m][n], 0, 0, 0);
    }
  }

  // epilogue: C/D layout col=lane&15, row=(lane>>4)*4+reg  [m89]
#pragma unroll
  for (int n = 0; n < 4; n++) {
    int colg = col0 + wc * 64 + n * 16 + l15;
    float bv = bias[(size_t)e * Ncols + colg];
#pragma unroll
    for (int m = 0; m < 4; m++) {
#pragma unroll
      for (int r = 0; r < 4; r++) {
        int row = wr * 64 + m * 16 + l4 * 4 + r;
        if (row < rows) {
          int tok = tok_s[row];
          float o = (acc[m][n][r] + bv) * p_s[row];
          if (Ybf) Ybf[(size_t)tok * Ncols + colg] = f2bf(o);
          else     Yf [(size_t)tok * Ncols + colg] = o;
        }
      }
    }
  }
}

// ---------------- MFMA attention --------------------------------------------------
// block = (qt, h, b), 256 thr = 4 waves. 32 q-rows, 512 keys, DH=64.
// QK: wave w -> keys w*16..+15 per 64-key tile; PV: wave w -> d-cols w*16..+15.
// S [32][520] bf16 holds scores then unnormalized exp; renorm deferred via invs[32].
__global__ __launch_bounds__(256) void attn_kernel(
    const unsigned short* __restrict__ qkvb, const int* __restrict__ attn_mask,
    const int* __restrict__ kp_mask, float* __restrict__ probs_out,
    unsigned short* __restrict__ ctxb) {
  int qt = blockIdx.x, h = blockIdx.y, b = blockIdx.z;
  int tid = threadIdx.x;

  __shared__ unsigned short Qs[32 * 72];
  __shared__ unsigned short KV[64 * 72];
  __shared__ unsigned short S[32 * 520];
  __shared__ float invs[32];

  int lane = tid & 63, wave = tid >> 6;
  int l15 = lane & 15, l4 = lane >> 4;

  // ---- Q stage, pre-scaled by 1/8 (exact pow2 on bf16) ----
  {
    int r = tid >> 3, c = (tid & 7) * 8;
    int t = b * Nseq + qt * 32 + r;
    uint4 v = *(const uint4*)(qkvb + (size_t)t * H3 + h * DHd + c);
    unsigned short* u = (unsigned short*)&v;
    unsigned short tmp[8];
#pragma unroll
    for (int j = 0; j < 8; j++) tmp[j] = f2bf(bf2f(u[j]) * 0.125f);
    *(uint4*)&Qs[r * 72 + c] = *(uint4*)tmp;
  }

  // ---- QK^T ----
  int kr0 = tid >> 3, kc0 = (tid & 7) * 8;       // K-stage rows 0..31
  int kr1 = kr0 + 32;                            // rows 32..63
  for (int kt = 0; kt < 8; kt++) {
    uint4 kv0 = *(const uint4*)(qkvb + (size_t)(b * Nseq + kt * 64 + kr0) * H3 + Hdim + h * DHd + kc0);
    uint4 kv1 = *(const uint4*)(qkvb + (size_t)(b * Nseq + kt * 64 + kr1) * H3 + Hdim + h * DHd + kc0);
    __syncthreads();   // prior tile's frag reads done (kt=0: orders Q write too)
    *(uint4*)&KV[kr0 * 72 + kc0] = kv0;
    *(uint4*)&KV[kr1 * 72 + kc0] = kv1;
    __syncthreads();

    f32x4 acc[2] = {};
#pragma unroll
    for (int kk = 0; kk < 2; kk++) {
      short8 bfr = *(const short8*)&KV[(wave * 16 + l15) * 72 + kk * 32 + l4 * 8];
#pragma unroll
      for (int m = 0; m < 2; m++) {
        short8 afr = *(const short8*)&Qs[(m * 16 + l15) * 72 + kk * 32 + l4 * 8];
        acc[m] = __builtin_amdgcn_mfma_f32_16x16x32_bf16(afr, bfr, acc[m], 0, 0, 0);
      }
    }
    // mask + store scores
    int key = kt * 64 + wave * 16 + l15;
    int kpm = kp_mask[b * Nseq + key];
#pragma unroll
    for (int m = 0; m < 2; m++) {
#pragma unroll
      for (int r = 0; r < 4; r++) {
        int row = m * 16 + l4 * 4 + r;
        int am = attn_mask[(qt * 32 + row) * Nseq + key];
        float sc = acc[m][r] + ((am | kpm) ? -10000.0f : 0.0f);
        S[row * 520 + key] = f2bf(sc);
      }
    }
  }
  __syncthreads();

  // ---- softmax: 8 lanes/row, vectorized; S <- exp(s-m) unnormalized ----
  float inv;
  int sr = tid >> 3, sg = tid & 7;
  {
    unsigned short* Srow = &S[sr * 520];
    float m = -3.0e38f;
#pragma unroll
    for (int i = 0; i < 8; i++) {
      uint4 v = *(const uint4*)&Srow[(sg + 8 * i) * 8];
      unsigned short* u = (unsigned short*)&v;
#pragma unroll
      for (int j = 0; j < 8; j++) m = fmaxf(m, bf2f(u[j]));
    }
#pragma unroll
    for (int off = 1; off < 8; off <<= 1) m = fmaxf(m, __shfl_xor(m, off));
    float sum = 0.f;
#pragma unroll
    for (int i = 0; i < 8; i++) {
      uint4 v = *(const uint4*)&Srow[(sg + 8 * i) * 8];
      unsigned short* u = (unsigned short*)&v;
      unsigned short t2[8];
#pragma unroll
      for (int j = 0; j < 8; j++) {
        float p = expf(bf2f(u[j]) - m);
        t2[j] = f2bf(p);
        sum += p;
      }
      *(uint4*)&Srow[(sg + 8 * i) * 8] = *(uint4*)t2;
    }
#pragma unroll
    for (int off = 1; off < 8; off <<= 1) sum += __shfl_xor(sum, off);
    inv = 1.0f / sum;
    if (sg == 0) invs[sr] = inv;
  }
  __syncthreads();

  // ---- probs out: fp32, normalized on the fly ----
  {
    float* dst = probs_out + (((size_t)(b * NHd + h) * Nseq + qt * 32 + sr) * Nseq);
    const unsigned short* Srow = &S[sr * 520];
#pragma unroll
    for (int i = 0; i < 8; i++) {
      int cb = (sg + 8 * i) * 8;
      uint4 v = *(const uint4*)&Srow[cb];
      unsigned short* u = (unsigned short*)&v;
      float4 o0 = {bf2f(u[0]) * inv, bf2f(u[1]) * inv, bf2f(u[2]) * inv, bf2f(u[3]) * inv};
      float4 o1 = {bf2f(u[4]) * inv, bf2f(u[5]) * inv, bf2f(u[6]) * inv, bf2f(u[7]) * inv};
      *(float4*)(dst + cb)     = o0;
      *(float4*)(dst + cb + 4) = o1;
    }
  }

  // ---- PV: ctx = (S @ V) * inv ----
  f32x4 acc2[2] = {};
  int kpair = tid & 31, vc = (tid >> 5) * 8;
  for (int kt = 0; kt < 8; kt++) {
    const unsigned short* vsrc =
        qkvb + (size_t)(b * Nseq + kt * 64 + kpair * 2) * H3 + 2 * Hdim + h * DHd + vc;
    uint4 v0 = *(const uint4*)vsrc;
    uint4 v1 = *(const uint4*)(vsrc + H3);
    __syncthreads();   // prior tile's frag reads done (kt=0: probs reads done)
    unsigned* a0 = (unsigned*)&v0;
    unsigned* a1 = (unsigned*)&v1;
#pragma unroll
    for (int i = 0; i < 4; i++) {
      unsigned lo = (a0[i] & 0xffffu) | (a1[i] << 16);
      unsigned hi = (a0[i] >> 16) | (a1[i] & 0xffff0000u);
      *(unsigned*)&KV[(vc + 2 * i    ) * 72 + 2 * kpair] = lo;   // Vt[d][keypair]
      *(unsigned*)&KV[(vc + 2 * i + 1) * 72 + 2 * kpair] = hi;
    }
    __syncthreads();
#pragma unroll
    for (int kk = 0; kk < 2; kk++) {
      short8 bfr = *(const short8*)&KV[(wave * 16 + l15) * 72 + kk * 32 + l4 * 8];
#pragma unroll
      for (int m = 0; m < 2; m++) {
        short8 pfr = *(const short8*)&S[(m * 16 + l15) * 520 + kt * 64 + kk * 32 + l4 * 8];
        acc2[m] = __builtin_amdgcn_mfma_f32_16x16x32_bf16(pfr, bfr, acc2[m], 0, 0, 0);
      }
    }
  }
#pragma unroll
  for (int m = 0; m < 2; m++) {
#pragma unroll
    for (int r = 0; r < 4; r++) {
      int row = m * 16 + l4 * 4 + r;
      int tq = b * Nseq + qt * 32 + row;
      ctxb[(size_t)tq * Hdim + h * DHd + wave * 16 + l15] = f2bf(acc2[m][r] * invs[row]);
    }
  }
}

// ---------------- host ------------------------------------------------------------
extern "C" void kernel_launch(void* const* d_in, const int* in_sizes, int n_in,
                              void* d_out, int out_size, void* d_ws, size_t ws_size,
                              hipStream_t stream) {
  const float* hidden   = (const float*)d_in[0];
  const int*   attn_m   = (const int*)d_in[1];
  const int*   kp_m     = (const int*)d_in[2];
  const float* w_gate   = (const float*)d_in[3];
  const float* w_qkv    = (const float*)d_in[4];
  const float* b_qkv    = (const float*)d_in[5];
  const float* w_dense  = (const float*)d_in[6];
  const float* b_dense  = (const float*)d_in[7];

  float* out       = (float*)d_out;                 // [T,H] fp32
  float* probs_out = out + (size_t)T * Hdim;        // [B,NH,N,N] fp32

  float*          prob = (float*)d_ws;
  unsigned short* Xb   = (unsigned short*)(prob + 2048);
  unsigned short* qkvb = Xb + (size_t)T * Hdim;
  unsigned short* ctxb = qkvb + (size_t)T * H3;
  int*   ip     = (int*)(ctxb + (size_t)T * Hdim);
  int*   expert = ip;
  int*   perm   = ip + T;
  int*   counts = ip + 2 * T;
  int*   offs   = counts + 8;
  int*   cursor = offs + 12;
  int*   meta   = cursor + 8;
  int*   tile_e = meta + 4;
  int*   tile_r = tile_e + MAX_T;

  init_kernel<<<1, 64, 0, stream>>>(counts);
  gate_kernel<<<T, 64, 0, stream>>>(hidden, w_gate, prob, expert, counts);
  offsets_kernel<<<1, 1, 0, stream>>>(counts, offs, cursor, meta, tile_e, tile_r);
  scatter_kernel<<<T / 256, 256, 0, stream>>>(expert, cursor, perm);
  cvt_kernel<<<(T * Hdim / 8) / 256, 256, 0, stream>>>(hidden, Xb, T * Hdim / 8);
  moe_gemm_mfma<<<dim3(H3 / 128, MAX_T), 256, 0, stream>>>(
      Xb, w_qkv, b_qkv, prob, perm, offs, meta, tile_e, tile_r, qkvb, nullptr, H3);
  attn_kernel<<<dim3(16, NHd, Bsz), 256, 0, stream>>>(qkvb, attn_m, kp_m, probs_out, ctxb);
  moe_gemm_mfma<<<dim3(Hdim / 128, MAX_T), 256, 0, stream>>>(
      ctxb, w_dense, b_dense, prob, perm, offs, meta, tile_e, tile_r, nullptr, out, Hdim);
}